// Round 9
// baseline (102.891 us; speedup 1.0000x reference)
//
#include <hip/hip_runtime.h>
#include <hip/hip_bf16.h>

#define D 128
#define RPW 2   // rows per wave in spmm

typedef __attribute__((ext_vector_type(8))) short bf16x8;
typedef __attribute__((ext_vector_type(4))) float f32x4;
typedef __attribute__((ext_vector_type(2))) unsigned u32x2;

// float -> bf16 bits, round-to-nearest-even (cold paths)
__device__ __forceinline__ unsigned short f2bf(float f) {
    union { float f; unsigned u; } uf{f};
    unsigned r = uf.u + 0x7fffu + ((uf.u >> 16) & 1u);
    return (unsigned short)(r >> 16);
}
// hot-path pack: v_cvt_pk_bf16_f32 via intrinsic (RNE)
__device__ __forceinline__ unsigned packcv(float a, float b) {
    __hip_bfloat162 h = __float22bfloat162_rn(make_float2(a, b));
    union { __hip_bfloat162 h; unsigned u; } c{h};
    return c.u;
}
__device__ __forceinline__ float bflo(unsigned u) {
    union { unsigned u; float f; } c{u << 16};
    return c.f;
}
__device__ __forceinline__ float bfhi(unsigned u) {
    union { unsigned u; float f; } c{u & 0xffff0000u};
    return c.f;
}
// decode packed (bf15<<17)|col
__device__ __forceinline__ int pc_col(unsigned u) { return (int)(u & 0x1FFFFu); }
__device__ __forceinline__ float pc_val(unsigned u) {
    union { unsigned u; float f; } c{(u >> 1) & 0xFFFF0000u};
    return c.f;
}

#define FMA8(A, vv, u) \
    A[0] = fmaf(vv, bflo(u.x), A[0]); A[1] = fmaf(vv, bfhi(u.x), A[1]); \
    A[2] = fmaf(vv, bflo(u.y), A[2]); A[3] = fmaf(vv, bfhi(u.y), A[3]); \
    A[4] = fmaf(vv, bflo(u.z), A[4]); A[5] = fmaf(vv, bfhi(u.z), A[5]); \
    A[6] = fmaf(vv, bflo(u.w), A[6]); A[7] = fmaf(vv, bfhi(u.w), A[7]);

// ---------------------------------------------------------------------------
// Kernel 0: rowptr from sorted adj_rows (+ gap fill); pack (val,col) -> u32;
//           convert W to bf16.
// ---------------------------------------------------------------------------
__global__ __launch_bounds__(256) void build_rowptr(const int* __restrict__ rows,
                                                    const int* __restrict__ cols,
                                                    const float* __restrict__ vals,
                                                    const float* __restrict__ W,
                                                    unsigned short* __restrict__ wbf,
                                                    unsigned* __restrict__ pc,
                                                    int2* __restrict__ rowptr,
                                                    int e, int n) {
    int i = blockIdx.x * 256 + threadIdx.x;
    if (i < D * D) wbf[i] = f2bf(W[i]);
    if (i >= e) return;

    // pack: vals in [0,1) -> positive bf16 (15 bits), col < 2^17
    pc[i] = ((unsigned)f2bf(vals[i]) << 17) | (unsigned)cols[i];

    int r = rows[i];
    int prev = (i == 0) ? -1 : rows[i - 1];
    int next = (i == e - 1) ? n : rows[i + 1];
    if (prev != r) {
        rowptr[r].x = i;
        for (int q = prev + 1; q < r; ++q) rowptr[q] = make_int2(i, i);   // empty rows
    }
    if (next != r) {
        rowptr[r].y = i + 1;
        if (i == e - 1)
            for (int q = r + 1; q < n; ++q) rowptr[q] = make_int2(e, e); // trailing empties
    }
}

// ---------------------------------------------------------------------------
// Kernel 1: wi = bf16(x @ W^T), MFMA with swapped operands (D = W·x^T).
//   x loads + wi stores non-temporal (pure streams, no L2 reuse value).
// ---------------------------------------------------------------------------
__global__ __launch_bounds__(256) void gemm_mfma(const float* __restrict__ x,
                                                 const unsigned short* __restrict__ wbf,
                                                 unsigned short* __restrict__ wi,
                                                 int nrows) {
    __shared__ __align__(16) unsigned short Ws[128 * 128];   // 32 KB, swizzled

    const int tid = threadIdx.x;
    const int lane = tid & 63;
    const int row0 = blockIdx.x * 128 + (tid >> 6) * 32;  // wave's 32 nodes
    const int lrow = lane & 15;
    const int lk8 = (lane >> 4) * 8;

    // 1) issue all x loads first (non-temporal: streaming, evict-first)
    f32x4 xf[2][4][2];
#pragma unroll
    for (int xb = 0; xb < 2; ++xb)
#pragma unroll
        for (int kb = 0; kb < 4; ++kb) {
            int gr = min(row0 + xb * 16 + lrow, nrows - 1);
            const f32x4* p = (const f32x4*)(x + (size_t)gr * D + kb * 32 + lk8);
            xf[xb][kb][0] = __builtin_nontemporal_load(p);
            xf[xb][kb][1] = __builtin_nontemporal_load(p + 1);
        }

    // 2) stage W into swizzled LDS (overlaps with x loads in flight)
#pragma unroll
    for (int it = 0; it < 8; ++it) {
        int elem = it * 2048 + tid * 8;
        int r = elem >> 7, k = elem & 127;
        int idx = (r * 128 + k) ^ ((r & 7) << 3);
        *(uint4*)&Ws[idx] = *(const uint4*)(wbf + elem);
    }
    __syncthreads();

    // 3) convert x to bf16 fragments
    bf16x8 xfrag[2][4];
#pragma unroll
    for (int xb = 0; xb < 2; ++xb)
#pragma unroll
        for (int kb = 0; kb < 4; ++kb) {
            f32x4 f0 = xf[xb][kb][0], f1 = xf[xb][kb][1];
            union { bf16x8 v; unsigned u[4]; } cv;
            cv.u[0] = packcv(f0.x, f0.y);
            cv.u[1] = packcv(f0.z, f0.w);
            cv.u[2] = packcv(f1.x, f1.y);
            cv.u[3] = packcv(f1.z, f1.w);
            xfrag[xb][kb] = cv.v;
        }

    f32x4 acc[2][8];
#pragma unroll
    for (int xb = 0; xb < 2; ++xb)
#pragma unroll
        for (int cb = 0; cb < 8; ++cb)
            acc[xb][cb] = (f32x4){0.f, 0.f, 0.f, 0.f};

#pragma unroll
    for (int cb = 0; cb < 8; ++cb) {
#pragma unroll
        for (int kb = 0; kb < 4; ++kb) {
            int wrow = cb * 16 + lrow;
            int idx = (wrow * 128 + kb * 32 + lk8) ^ ((wrow & 7) << 3);
            bf16x8 wfrag = *(const bf16x8*)&Ws[idx];
            acc[0][cb] = __builtin_amdgcn_mfma_f32_16x16x32_bf16(wfrag, xfrag[0][kb], acc[0][cb], 0, 0, 0);
            acc[1][cb] = __builtin_amdgcn_mfma_f32_16x16x32_bf16(wfrag, xfrag[1][kb], acc[1][cb], 0, 0, 0);
        }
    }

    // D layout: col(lane&15)=node, row((lane>>4)*4+j)=channel
#pragma unroll
    for (int xb = 0; xb < 2; ++xb) {
        int g = row0 + xb * 16 + lrow;
        if (g < nrows) {
#pragma unroll
            for (int cb = 0; cb < 8; ++cb) {
                u32x2 o;
                o.x = packcv(acc[xb][cb][0], acc[xb][cb][1]);
                o.y = packcv(acc[xb][cb][2], acc[xb][cb][3]);
                __builtin_nontemporal_store(o, (u32x2*)(wi + (size_t)g * D + cb * 16 + (lane >> 4) * 4));
            }
        }
    }
}

// ---------------------------------------------------------------------------
// Kernel 2: out[r] = relu(bias + sum vals[e]*wi[cols[e]])  (wi bf16, pc packed)
//   pc loads + out stores non-temporal so the streams don't evict wi from L2;
//   gather loads stay cacheable.
// ---------------------------------------------------------------------------
__global__ __launch_bounds__(256) void spmm_relu(const unsigned short* __restrict__ wi,
                                                 const int2* __restrict__ rowptr,
                                                 const unsigned* __restrict__ pc,
                                                 const float* __restrict__ bias,
                                                 float* __restrict__ out,
                                                 int n) {
    const int lane = threadIdx.x & 63;
    const int R0 = (blockIdx.x * 4 + (threadIdx.x >> 6)) * RPW;
    if (R0 >= n) return;
    const int nr = min(RPW, n - R0);

    const int2 rp = rowptr[R0 + min(lane, nr - 1)];
    const int ch = (lane & 15) * 8;   // channel base this lane gathers
    const int sub = lane >> 4;        // lane's slot within each quad

    float4 b0 = *(const float4*)(bias + (lane & 15) * 8);
    float4 b1 = *(const float4*)(bias + (lane & 15) * 8 + 4);

    // prologue: stage row 0's first chunk (coalesced, nt)
    int st = __shfl(rp.x, 0), en = __shfl(rp.y, 0);
    unsigned u = 0;
    { int idx = st + lane; if (idx < en) u = __builtin_nontemporal_load(pc + idx); }

    for (int j = 0; j < nr; ++j) {
        // prefetch next row's metadata
        int st_n = 0, en_n = 0; unsigned u_n = 0;
        if (j + 1 < nr) {
            st_n = __shfl(rp.x, j + 1); en_n = __shfl(rp.y, j + 1);
            int idx = st_n + lane; if (idx < en_n) u_n = __builtin_nontemporal_load(pc + idx);
        }

        float a0[8] = {0.f, 0.f, 0.f, 0.f, 0.f, 0.f, 0.f, 0.f};
        float a1[8] = {0.f, 0.f, 0.f, 0.f, 0.f, 0.f, 0.f, 0.f};

        const int cnt = min(en - st, 64);
        if (cnt > 0) {
            // edges [0,32): both quads issued together -> 8 gathers in flight.
            unsigned mA[4], mB[4];
#pragma unroll
            for (int p = 0; p < 4; ++p) {
                mA[p] = __shfl(u, sub + 4 * p);
                mB[p] = __shfl(u, 16 + sub + 4 * p);
            }
            uint4 uA[4], uB[4];
#pragma unroll
            for (int p = 0; p < 4; ++p) uA[p] = *(const uint4*)(wi + (size_t)pc_col(mA[p]) * D + ch);
#pragma unroll
            for (int p = 0; p < 4; ++p) uB[p] = *(const uint4*)(wi + (size_t)pc_col(mB[p]) * D + ch);
#pragma unroll
            for (int p = 0; p < 4; ++p) {
                FMA8(a0, pc_val(mA[p]), uA[p]);
                FMA8(a1, pc_val(mB[p]), uB[p]);
            }
            // edges [32, cnt): rows with >32 edges
            for (int E = 32; E < cnt; E += 16) {
#pragma unroll
                for (int p = 0; p < 4; ++p) {
                    unsigned m = __shfl(u, E + sub + 4 * p);
                    uint4 uq = *(const uint4*)(wi + (size_t)pc_col(m) * D + ch);
                    FMA8(a0, pc_val(m), uq);
                }
            }
        }
        // very rare rows with >64 edges
        for (int base = st + 64; base < en; base += 64) {
            unsigned uu = 0;
            { int idx = base + lane; if (idx < en) uu = __builtin_nontemporal_load(pc + idx); }
            const int cnt2 = min(en - base, 64);
            for (int E = 0; E < cnt2; E += 16) {
#pragma unroll
                for (int p = 0; p < 4; ++p) {
                    unsigned m = __shfl(uu, E + sub + 4 * p);
                    uint4 uq = *(const uint4*)(wi + (size_t)pc_col(m) * D + ch);
                    FMA8(a1, pc_val(m), uq);
                }
            }
        }

        // reduce across the 4 sub-groups + store (nt)
        float r8[8];
#pragma unroll
        for (int t = 0; t < 8; ++t) {
            float s = a0[t] + a1[t];
            s += __shfl_xor(s, 16);
            s += __shfl_xor(s, 32);
            r8[t] = s;
        }
        if (lane < 16) {
            f32x4 o0, o1;
            o0.x = fmaxf(r8[0] + b0.x, 0.f);
            o0.y = fmaxf(r8[1] + b0.y, 0.f);
            o0.z = fmaxf(r8[2] + b0.z, 0.f);
            o0.w = fmaxf(r8[3] + b0.w, 0.f);
            o1.x = fmaxf(r8[4] + b1.x, 0.f);
            o1.y = fmaxf(r8[5] + b1.y, 0.f);
            o1.z = fmaxf(r8[6] + b1.z, 0.f);
            o1.w = fmaxf(r8[7] + b1.w, 0.f);
            float* op = out + (size_t)(R0 + j) * D + lane * 8;
            __builtin_nontemporal_store(o0, (f32x4*)op);
            __builtin_nontemporal_store(o1, (f32x4*)(op + 4));
        }

        st = st_n; en = en_n; u = u_n;
    }
}

// ---------------------------------------------------------------------------
extern "C" void kernel_launch(void* const* d_in, const int* in_sizes, int n_in,
                              void* d_out, int out_size, void* d_ws, size_t ws_size,
                              hipStream_t stream) {
    const float* x        = (const float*)d_in[0];
    const int*   adj_rows = (const int*)d_in[1];
    const int*   adj_cols = (const int*)d_in[2];
    const float* adj_vals = (const float*)d_in[3];
    const float* weight   = (const float*)d_in[4];
    const float* bias     = (const float*)d_in[5];
    float*       out      = (float*)d_out;

    const int n = in_sizes[0] / D;   // 100000
    const int e = in_sizes[1];       // 1600000

    // workspace layout
    unsigned short* wi = (unsigned short*)d_ws;                 // n*128 bf16 = 25.6 MB
    size_t off = ((size_t)n * D * sizeof(unsigned short) + 255) & ~(size_t)255;
    int2* rowptr = (int2*)((char*)d_ws + off);                  // n int2 = 0.8 MB
    unsigned* pc = (unsigned*)(rowptr + n);                     // e u32 = 6.4 MB
    unsigned short* wbf = (unsigned short*)(pc + e);            // 32 KB bf16 W

    build_rowptr<<<(e + 255) / 256, 256, 0, stream>>>(adj_rows, adj_cols, adj_vals,
                                                      weight, wbf, pc, rowptr, e, n);

    gemm_mfma<<<(n + 127) / 128, 256, 0, stream>>>(x, wbf, wi, n);

    spmm_relu<<<(n + 4 * RPW - 1) / (4 * RPW), 256, 0, stream>>>(
        wi, rowptr, pc, bias, out, n);
}